// Round 1
// baseline (236.946 us; speedup 1.0000x reference)
//
#include <hip/hip_runtime.h>
#include <stdint.h>

// IDCT (DCT-III, DREAMPlace scaling) via even/odd split, fully fused:
//   E[m][p] = sum_{n even} x[m][n]*c(n,p),  O[m][p] = sum_{n odd} ...,
//   out[p] = E+O, out[N-1-p] = E-O   (c(n,N-1-p) = (-1)^n c(n,p)).
// R6: two changes driven by rocprof.
//  (1) gemm was LDS-read-bound: SQ_LDS_BANK_CONFLICT=2.5e7/dispatch (~3000
//      cyc/CU/K-iter, 42% of iter time). Old row-major [row][BK=64] tiles put
//      lanes 0-15 of every ds_read_b128 on one 4-bank group (16-way conflict).
//      New: fragment-contiguous LDS layout — chunk c (16B) holds element
//      (row=16*(c>>7)+(c&15), k=32*((c>>6)&1)+8*((c>>4)&3)), so every frag
//      read is wave_base + lane*16B = contiguous 1KB, conflict-free. Achieved
//      by permuting the per-lane GLOBAL source of global_load_lds (the LDS
//      dst stays linear, as the hardware requires).
//  (2) prep was ~95us (total 195 - gemm 98), 5x over its 18us BW roofline and
//      invisible in top-5 (gemm always edged it out). Rewritten: 64B/thread
//      reads, 16B int4 stores for both deinterleave halves, 8192 blocks.
// ws: [0,32MB) A' bf16 (even cols | odd cols), [32,40) Ce, [40,48) Co.

#define Md 4096
#define Nfull 4096
#define Ph 2048   // half output width
#define Kh 2048   // half reduction
#define BM 128
#define BN 128
#define BK 64

typedef short bf16x8 __attribute__((ext_vector_type(8)));
typedef float floatx4 __attribute__((ext_vector_type(4)));
typedef unsigned short ushort_t;

__device__ __forceinline__ ushort_t f2bf(float f) {
  union { float f; uint32_t u; } v; v.f = f;
  uint32_t u = v.u;
  return (ushort_t)((u + 0x7fffu + ((u >> 16) & 1u)) >> 16);
}

// blocks [0,4096): x fp32 -> bf16 even/odd column deinterleave, 16 elems/thr
//   (64B read, two 16B stores).
// blocks [4096,8192): fill Ce[p][ne]=c(2ne,p), Co[p][no]=c(2no+1,p), 8/thr.
__global__ __launch_bounds__(256) void prep_kernel(const float* __restrict__ x,
                                                   ushort_t* __restrict__ A,
                                                   ushort_t* __restrict__ Ce,
                                                   ushort_t* __restrict__ Co) {
  int b = blockIdx.x;
  int tid = threadIdx.x;
  if (b < 4096) {
    int i = (b * 256 + tid) * 16;
    int m = i >> 12;
    int j = i & 4095;
    const float4* xp = (const float4*)(x + i);
    float4 a0 = xp[0];
    float4 a1 = xp[1];
    float4 a2 = xp[2];
    float4 a3 = xp[3];
    union { ushort_t us[8]; int4 v; } ev, od;
    ev.us[0] = f2bf(a0.x); od.us[0] = f2bf(a0.y);
    ev.us[1] = f2bf(a0.z); od.us[1] = f2bf(a0.w);
    ev.us[2] = f2bf(a1.x); od.us[2] = f2bf(a1.y);
    ev.us[3] = f2bf(a1.z); od.us[3] = f2bf(a1.w);
    ev.us[4] = f2bf(a2.x); od.us[4] = f2bf(a2.y);
    ev.us[5] = f2bf(a2.z); od.us[5] = f2bf(a2.w);
    ev.us[6] = f2bf(a3.x); od.us[6] = f2bf(a3.y);
    ev.us[7] = f2bf(a3.z); od.us[7] = f2bf(a3.w);
    int half = j >> 1;   // multiple of 8 -> 16B aligned
    *(int4*)(A + (size_t)m * Nfull + half) = ev.v;
    *(int4*)(A + (size_t)m * Nfull + Ph + half) = od.v;
  } else {
    int idx = ((b - 4096) * 256 + tid) * 8;  // [0, 8M)
    const float s = 3.14159265358979f / 8192.0f;  // pi/(2N)
    union { ushort_t us[8]; int4 v; } pk;
    if (idx < Ph * Kh) {               // Ce
      int p = idx >> 11;
      int ne0 = idx & 2047;
      int tp = 2 * p + 1;
#pragma unroll
      for (int jj = 0; jj < 8; ++jj) {
        int n = 2 * (ne0 + jj);
        int t = (n * tp) & 16383;      // mod 4N: exact int reduction
        float c = (n == 0) ? 1.0f : 2.0f * __cosf(s * (float)t);
        pk.us[jj] = f2bf(c);
      }
      *(int4*)(Ce + idx) = pk.v;
    } else {                           // Co
      int local = idx - Ph * Kh;
      int p = local >> 11;
      int no0 = local & 2047;
      int tp = 2 * p + 1;
#pragma unroll
      for (int jj = 0; jj < 8; ++jj) {
        int n = 2 * (no0 + jj) + 1;
        int t = (n * tp) & 16383;
        pk.us[jj] = f2bf(2.0f * __cosf(s * (float)t));
      }
      *(int4*)(Co + local) = pk.v;
    }
  }
}

// Fused dual GEMM + butterfly. Block tile 128m x 128p, BK=64, 4 waves 2x2,
// wave tile 64x64 per GEMM, frags 4x4, dual acc E/O (128 acc VGPRs).
//
// LDS layout (fragment-contiguous, per 16KB tile): 16B chunk c holds
//   row = 16*(c>>7) + (c&15),  k = 32*((c>>6)&1) + 8*((c>>4)&3)  (8 bf16).
// Staging: GLDS writes lane l of issue i at chunk c = i*256 + wid*64 + l
// (linear), so each lane fetches the global element for ITS chunk:
//   srow = 16*(c>>7)+(c&15), scol = 32*kk + 8*q  -> precomputed per thread.
// Fragment read for (R,kk): lane wants (row=16R+(lane&15), k=32kk+8*(lane>>4))
//   -> LDS elem offset R*1024 + kk*512 + lane*8: contiguous 1KB per wave,
//   ZERO bank conflicts (was 16-way at the old [row][64] layout).
__global__ __launch_bounds__(256, 2) void gemm_fused(const ushort_t* __restrict__ A,
                                                     const ushort_t* __restrict__ Ce,
                                                     const ushort_t* __restrict__ Co,
                                                     float* __restrict__ out) {
  __shared__ __align__(16) ushort_t AsE[BM * BK];   // 16 KB
  __shared__ __align__(16) ushort_t AsO[BM * BK];   // 16 KB
  __shared__ __align__(16) ushort_t BsE[BN * BK];   // 16 KB
  __shared__ __align__(16) ushort_t BsO[BN * BK];   // 16 KB  -> 64 KB total

  const int tid = threadIdx.x;
  const int wid = tid >> 6;
  const int lane = tid & 63;

  const int bm = blockIdx.y * BM;
  const int bn = blockIdx.x * BN;

  const int wm = (wid & 1) * 64;
  const int wn = (wid >> 1) * 64;

  const int lrow = lane & 15;

  floatx4 accE[4][4] = {};
  floatx4 accO[4][4] = {};

  // Staging source coords for this thread's chunk (c = i*256 + tid):
  //   c&127 == tid&127 (since 256 ≡ 0 mod 128), R = 2i + (tid>>7).
  const int srow = ((tid >> 7) << 4) | (tid & 15);          // +32 per issue
  const int scol = ((tid >> 6) & 1) * 32 + ((tid >> 4) & 3) * 8;
  const int lb = wid * 512;                                 // LDS elem base/8

  const ushort_t* Ae = A + (size_t)bm * Nfull;        // even half, row stride 4096
  const ushort_t* Ao = Ae + Ph;                       // odd half
  const ushort_t* Be = Ce + (size_t)bn * Kh;          // row stride 2048
  const ushort_t* Bo = Co + (size_t)bn * Kh;

  const size_t aoff0 = (size_t)srow * Nfull + scol;
  const size_t boff0 = (size_t)srow * Kh + scol;

#define GLDS(src, dst) __builtin_amdgcn_global_load_lds( \
      (const __attribute__((address_space(1))) void*)(src), \
      (__attribute__((address_space(3))) void*)(dst), 16, 0, 0)

  for (int k0 = 0; k0 < Kh; k0 += BK) {
#pragma unroll
    for (int i = 0; i < 4; ++i) {      // 4 issues per matrix
      size_t ao = aoff0 + (size_t)(i * 32) * Nfull + k0;
      size_t bo = boff0 + (size_t)(i * 32) * Kh + k0;
      int l = i * 2048 + lb;
      GLDS(Ae + ao, AsE + l);
      GLDS(Ao + ao, AsO + l);
      GLDS(Be + bo, BsE + l);
      GLDS(Bo + bo, BsO + l);
    }
    __syncthreads();   // drains vmcnt -> staging visible

#pragma unroll
    for (int kk = 0; kk < 2; ++kk) {   // two K=32 sub-steps
      bf16x8 bE[4], bO[4];
#pragma unroll
      for (int f = 0; f < 4; ++f) {
        int off = ((wn >> 4) + f) * 1024 + kk * 512 + lane * 8;
        bE[f] = *(const bf16x8*)(BsE + off);
        bO[f] = *(const bf16x8*)(BsO + off);
      }
#pragma unroll
      for (int im = 0; im < 4; ++im) {
        int off = ((wm >> 4) + im) * 1024 + kk * 512 + lane * 8;
        bf16x8 aE = *(const bf16x8*)(AsE + off);
        bf16x8 aO = *(const bf16x8*)(AsO + off);
#pragma unroll
        for (int jn = 0; jn < 4; ++jn) {
          accE[im][jn] = __builtin_amdgcn_mfma_f32_16x16x32_bf16(aE, bE[jn], accE[im][jn], 0, 0, 0);
          accO[im][jn] = __builtin_amdgcn_mfma_f32_16x16x32_bf16(aO, bO[jn], accO[im][jn], 0, 0, 0);
        }
      }
    }
    __syncthreads();   // all waves done reading before next overwrite
  }
#undef GLDS

  // Epilogue butterfly. C/D mapping: col=lane&15, row=(lane>>4)*4+r.
#pragma unroll
  for (int im = 0; im < 4; ++im) {
    int rb = bm + wm + im * 16 + (lane >> 4) * 4;
#pragma unroll
    for (int jn = 0; jn < 4; ++jn) {
      int p = bn + wn + jn * 16 + lrow;
      float* lo = out + (size_t)rb * Nfull + p;
      float* hi = out + (size_t)rb * Nfull + (Nfull - 1 - p);
#pragma unroll
      for (int r = 0; r < 4; ++r) {
        float e = accE[im][jn][r];
        float o = accO[im][jn][r];
        lo[(size_t)r * Nfull] = e + o;
        hi[(size_t)r * Nfull] = e - o;
      }
    }
  }
}

extern "C" void kernel_launch(void* const* d_in, const int* in_sizes, int n_in,
                              void* d_out, int out_size, void* d_ws, size_t ws_size,
                              hipStream_t stream) {
  const float* x = (const float*)d_in[0];
  float* out = (float*)d_out;
  ushort_t* Axb = (ushort_t*)d_ws;                     // 32 MB
  ushort_t* Ce = Axb + (size_t)Md * Nfull;             // 8 MB
  ushort_t* Co = Ce + (size_t)Ph * Kh;                 // 8 MB

  prep_kernel<<<8192, 256, 0, stream>>>(x, Axb, Ce, Co);

  dim3 grid(Ph / BN, Md / BM);  // 16 x 32 = 512 blocks = 2/CU
  gemm_fused<<<grid, 256, 0, stream>>>(Axb, Ce, Co, out);
}

// Round 2
// 182.672 us; speedup vs baseline: 1.2971x; 1.2971x over previous
//
#include <hip/hip_runtime.h>
#include <stdint.h>

// IDCT (DCT-III, DREAMPlace scaling) via even/odd split, fully fused:
//   E[m][p] = sum_{n even} x[m][n]*c(n,p),  O[m][p] = sum_{n odd} ...,
//   out[p] = E+O, out[N-1-p] = E-O   (c(n,N-1-p) = (-1)^n c(n,p)).
// R7:
//  (1) gemm: revert to R5's global access pattern (8 rows x 128B per wave
//      GLDS issue — R6's 16x64B halved segment size and regressed 40%), and
//      add a BOTH-SIDES XOR chunk swizzle: staging lane fetches global chunk
//      (tid&7)^(row&7) of its row (row chunk-set unchanged -> coalescing
//      identical to R5), reads address chunk g^(row&7). Removes the 8-way
//      ds_read_b128 phase conflict (bank = 4*chunk only; row*128B ≡ bank 0).
//      LDS model: 32KB read/wave/K-iter -> this kernel is LDS-BW-bound
//      (~3000cy floor vs ~620cy MFMA), so conflict removal is a direct win:
//      predicted ~55-70us (R5 conflicted: 98us ~= 2.9x on the read term).
//  (2) prep split into prep_x / prep_tab for rocprof attribution: total-gemm
//      was ~97-99us in BOTH prior rounds (roofline 18us) and invariant to a
//      big deinterleave rewrite -> need per-kernel counters to see which
//      half is broken.
// ws: [0,32MB) A' bf16 (even cols | odd cols), [32,40) Ce, [40,48) Co.

#define Md 4096
#define Nfull 4096
#define Ph 2048   // half output width
#define Kh 2048   // half reduction
#define BM 128
#define BN 128
#define BK 64

typedef short bf16x8 __attribute__((ext_vector_type(8)));
typedef float floatx4 __attribute__((ext_vector_type(4)));
typedef unsigned short ushort_t;

__device__ __forceinline__ ushort_t f2bf(float f) {
  union { float f; uint32_t u; } v; v.f = f;
  uint32_t u = v.u;
  return (ushort_t)((u + 0x7fffu + ((u >> 16) & 1u)) >> 16);
}

// x fp32 -> bf16 even/odd column deinterleave, 16 elems/thread
// (64B read, two 16B stores). 4096 blocks.
__global__ __launch_bounds__(256) void prep_x(const float* __restrict__ x,
                                              ushort_t* __restrict__ A) {
  int i = (blockIdx.x * 256 + threadIdx.x) * 16;
  int m = i >> 12;
  int j = i & 4095;
  const float4* xp = (const float4*)(x + i);
  float4 a0 = xp[0];
  float4 a1 = xp[1];
  float4 a2 = xp[2];
  float4 a3 = xp[3];
  union { ushort_t us[8]; int4 v; } ev, od;
  ev.us[0] = f2bf(a0.x); od.us[0] = f2bf(a0.y);
  ev.us[1] = f2bf(a0.z); od.us[1] = f2bf(a0.w);
  ev.us[2] = f2bf(a1.x); od.us[2] = f2bf(a1.y);
  ev.us[3] = f2bf(a1.z); od.us[3] = f2bf(a1.w);
  ev.us[4] = f2bf(a2.x); od.us[4] = f2bf(a2.y);
  ev.us[5] = f2bf(a2.z); od.us[5] = f2bf(a2.w);
  ev.us[6] = f2bf(a3.x); od.us[6] = f2bf(a3.y);
  ev.us[7] = f2bf(a3.z); od.us[7] = f2bf(a3.w);
  int half = j >> 1;   // multiple of 8 -> 16B aligned
  *(int4*)(A + (size_t)m * Nfull + half) = ev.v;
  *(int4*)(A + (size_t)m * Nfull + Ph + half) = od.v;
}

// Cosine tables: Ce[p][ne]=c(2ne,p), Co[p][no]=c(2no+1,p), 8 elems/thread.
// 4096 blocks.
__global__ __launch_bounds__(256) void prep_tab(ushort_t* __restrict__ Ce,
                                                ushort_t* __restrict__ Co) {
  int idx = (blockIdx.x * 256 + threadIdx.x) * 8;  // [0, 8M)
  const float s = 3.14159265358979f / 8192.0f;     // pi/(2N)
  union { ushort_t us[8]; int4 v; } pk;
  if (idx < Ph * Kh) {               // Ce
    int p = idx >> 11;
    int ne0 = idx & 2047;
    int tp = 2 * p + 1;
#pragma unroll
    for (int jj = 0; jj < 8; ++jj) {
      int n = 2 * (ne0 + jj);
      int t = (n * tp) & 16383;      // mod 4N: exact int reduction
      float c = (n == 0) ? 1.0f : 2.0f * __cosf(s * (float)t);
      pk.us[jj] = f2bf(c);
    }
    *(int4*)(Ce + idx) = pk.v;
  } else {                           // Co
    int local = idx - Ph * Kh;
    int p = local >> 11;
    int no0 = local & 2047;
    int tp = 2 * p + 1;
#pragma unroll
    for (int jj = 0; jj < 8; ++jj) {
      int n = 2 * (no0 + jj) + 1;
      int t = (n * tp) & 16383;
      pk.us[jj] = f2bf(2.0f * __cosf(s * (float)t));
    }
    *(int4*)(Co + local) = pk.v;
  }
}

// Fused dual GEMM + butterfly. Block tile 128m x 128p, BK=64, 4 waves 2x2,
// wave tile 64x64 per GEMM, frags 4x4, dual acc E/O (128 acc VGPRs).
//
// LDS tiles row-major [row][64 elems], but each row's eight 16B chunks are
// stored XOR-permuted: LDS[row][pos] = global chunk (pos ^ (row&7)).
//   staging: lane fetches global chunk (tid&7)^(row&7)   (row chunk-set is
//            a bijection -> still full 128B/row coalescing, linear LDS dst)
//   reading: chunk g of row -> LDS pos g^(row&7); row&7 == lane&7 for all
//            fragment rows, so the XOR is one VALU op per kk.
// Bank math: byte = row*128 + pos*16 -> bank = 4*pos. Each consecutive-8-lane
// phase has pos = const ^ (0..7) = all 8 chunks -> all 32 banks, 0 conflicts
// (R5's unswizzled pos was constant per 8 lanes -> 8-way conflict = the
// 2.5e7 SQ_LDS_BANK_CONFLICT).
__global__ __launch_bounds__(256, 2) void gemm_fused(const ushort_t* __restrict__ A,
                                                     const ushort_t* __restrict__ Ce,
                                                     const ushort_t* __restrict__ Co,
                                                     float* __restrict__ out) {
  __shared__ __align__(16) ushort_t AsE[BM * BK];   // 16 KB
  __shared__ __align__(16) ushort_t AsO[BM * BK];   // 16 KB
  __shared__ __align__(16) ushort_t BsE[BN * BK];   // 16 KB
  __shared__ __align__(16) ushort_t BsO[BN * BK];   // 16 KB  -> 64 KB total

  const int tid = threadIdx.x;
  const int wid = tid >> 6;
  const int lane = tid & 63;

  const int bm = blockIdx.y * BM;
  const int bn = blockIdx.x * BN;

  const int wm = (wid & 1) * 64;
  const int wn = (wid >> 1) * 64;

  const int lrow = lane & 15;

  floatx4 accE[4][4] = {};
  floatx4 accO[4][4] = {};

  // Staging: chunk c = i*256+tid -> row = i*32 + (tid>>3), LDS pos = tid&7.
  // Source chunk = (tid&7) ^ (row&7); row&7 = (tid>>3)&7 (i*32 ≡ 0 mod 8).
  const int rr = tid >> 3;                                   // 0..31
  const int scol = ((tid & 7) ^ ((tid >> 3) & 7)) * 8;       // swizzled src elems
  const int lb = wid * 512;                                  // LDS elem base

  const ushort_t* Ae = A + (size_t)bm * Nfull;        // even half, row stride 4096
  const ushort_t* Ao = Ae + Ph;                       // odd half
  const ushort_t* Be = Ce + (size_t)bn * Kh;          // row stride 2048
  const ushort_t* Bo = Co + (size_t)bn * Kh;

#define GLDS(src, dst) __builtin_amdgcn_global_load_lds( \
      (const __attribute__((address_space(1))) void*)(src), \
      (__attribute__((address_space(3))) void*)(dst), 16, 0, 0)

  for (int k0 = 0; k0 < Kh; k0 += BK) {
#pragma unroll
    for (int i = 0; i < 4; ++i) {      // 4 issues per matrix
      int r = i * 32 + rr;
      int l = i * 2048 + lb;
      GLDS(Ae + (size_t)r * Nfull + k0 + scol, AsE + l);
      GLDS(Ao + (size_t)r * Nfull + k0 + scol, AsO + l);
      GLDS(Be + (size_t)r * Kh   + k0 + scol, BsE + l);
      GLDS(Bo + (size_t)r * Kh   + k0 + scol, BsO + l);
    }
    __syncthreads();   // drains vmcnt -> staging visible

#pragma unroll
    for (int kk = 0; kk < 2; ++kk) {   // two K=32 sub-steps
      // global chunk g = kk*4 + (lane>>4); LDS pos = g ^ (row&7), row&7==lane&7
      const int sg = ((kk * 4 + (lane >> 4)) ^ (lane & 7)) * 8;
      bf16x8 bE[4], bO[4];
#pragma unroll
      for (int f = 0; f < 4; ++f) {
        int off = (wn + f * 16 + lrow) * BK + sg;
        bE[f] = *(const bf16x8*)(BsE + off);
        bO[f] = *(const bf16x8*)(BsO + off);
      }
#pragma unroll
      for (int im = 0; im < 4; ++im) {
        int off = (wm + im * 16 + lrow) * BK + sg;
        bf16x8 aE = *(const bf16x8*)(AsE + off);
        bf16x8 aO = *(const bf16x8*)(AsO + off);
#pragma unroll
        for (int jn = 0; jn < 4; ++jn) {
          accE[im][jn] = __builtin_amdgcn_mfma_f32_16x16x32_bf16(aE, bE[jn], accE[im][jn], 0, 0, 0);
          accO[im][jn] = __builtin_amdgcn_mfma_f32_16x16x32_bf16(aO, bO[jn], accO[im][jn], 0, 0, 0);
        }
      }
    }
    __syncthreads();   // all waves done reading before next overwrite
  }
#undef GLDS

  // Epilogue butterfly. C/D mapping: col=lane&15, row=(lane>>4)*4+r.
#pragma unroll
  for (int im = 0; im < 4; ++im) {
    int rb = bm + wm + im * 16 + (lane >> 4) * 4;
#pragma unroll
    for (int jn = 0; jn < 4; ++jn) {
      int p = bn + wn + jn * 16 + lrow;
      float* lo = out + (size_t)rb * Nfull + p;
      float* hi = out + (size_t)rb * Nfull + (Nfull - 1 - p);
#pragma unroll
      for (int r = 0; r < 4; ++r) {
        float e = accE[im][jn][r];
        float o = accO[im][jn][r];
        lo[(size_t)r * Nfull] = e + o;
        hi[(size_t)r * Nfull] = e - o;
      }
    }
  }
}

extern "C" void kernel_launch(void* const* d_in, const int* in_sizes, int n_in,
                              void* d_out, int out_size, void* d_ws, size_t ws_size,
                              hipStream_t stream) {
  const float* x = (const float*)d_in[0];
  float* out = (float*)d_out;
  ushort_t* Axb = (ushort_t*)d_ws;                     // 32 MB
  ushort_t* Ce = Axb + (size_t)Md * Nfull;             // 8 MB
  ushort_t* Co = Ce + (size_t)Ph * Kh;                 // 8 MB

  prep_x<<<4096, 256, 0, stream>>>(x, Axb);
  prep_tab<<<4096, 256, 0, stream>>>(Ce, Co);

  dim3 grid(Ph / BN, Md / BM);  // 16 x 32 = 512 blocks = 2/CU
  gemm_fused<<<grid, 256, 0, stream>>>(Axb, Ce, Co, out);
}

// Round 3
// 178.578 us; speedup vs baseline: 1.3269x; 1.0229x over previous
//
#include <hip/hip_runtime.h>
#include <stdint.h>

// IDCT (DCT-III, DREAMPlace scaling) via even/odd split, fully fused:
//   E[m][p] = sum_{n even} x[m][n]*c(n,p),  O[m][p] = sum_{n odd} ...,
//   out[p] = E+O, out[N-1-p] = E-O   (c(n,N-1-p) = (-1)^n c(n,p)).
// R8 (from R7's counters: conflicts 0, gemm 76us, MfmaUtil 38%):
//  (1) gemm floors per CU: MFMA 33us, LDS-read 41us -> the extra ~30us is
//      the per-iter vmcnt(0) barrier drain (stage issued then immediately
//      waited). Fix: BK=32 + double-buffered LDS (2x32KB, still 2 blk/CU),
//      prefetch STAGE(t+1) BEFORE compute(t), ONE __syncthreads per iter
//      (T3-minimum 2-phase recipe, m230/m248-verified pattern).
//  (2) operands are pre-tiled by prep into k-major 8KB tiles that are the
//      EXACT LDS image: GLDS sources become fully linear (1KB contiguous
//      per wave-issue), fragment ds_reads 256B-contiguous per 16-lane
//      phase -> zero bank conflicts with no XOR anywhere. Per-lane (row,k)
//      data identical to R7 -> numerics unchanged.
//  (3) preps re-merged into ONE kernel: splitting them in R7 serialized two
//      small kernels and cost ~8-10us (total-gemm 96.6 -> 106.7).
// ws: Ae_t 16MB | Ao_t 16MB | Ce_t 8MB | Co_t 8MB = 48MB.
// Tile layout: plane[(tile = bt*64 + kb)*4096 + g*1024 + r*8 + j]
//   = elem(row=r, k=kb*32+g*8+j) of the (bt,kb) 128x32 tile.

#define Md 4096
#define Nfull 4096
#define Ph 2048   // half output width
#define Kh 2048   // half reduction
#define BM 128
#define BN 128
#define BK 32
#define NKB 64    // Kh/BK k-blocks
#define TILE 4096 // elems per tile (128 rows x 32 k)

typedef short bf16x8 __attribute__((ext_vector_type(8)));
typedef float floatx4 __attribute__((ext_vector_type(4)));
typedef unsigned short ushort_t;

__device__ __forceinline__ ushort_t f2bf(float f) {
  union { float f; uint32_t u; } v; v.f = f;
  uint32_t u = v.u;
  return (ushort_t)((u + 0x7fffu + ((u >> 16) & 1u)) >> 16);
}

// blocks [0,2048): deinterleave x into tiled Ae/Ao. Block=(bm,kb) tile pair;
//   thread t: row r=t>>1, half h=t&1 -> reads 32 consecutive floats (128B),
//   writes 2 int4 per plane at tiled offsets (two 512B segments/instr).
// blocks [2048,4096): cosine tables straight into tiled layout, 2 chunks/thr.
__global__ __launch_bounds__(256) void prep_kernel(const float* __restrict__ x,
                                                   ushort_t* __restrict__ Ae,
                                                   ushort_t* __restrict__ Ao,
                                                   ushort_t* __restrict__ Ce,
                                                   ushort_t* __restrict__ Co) {
  int b = blockIdx.x;
  int t = threadIdx.x;
  if (b < 2048) {
    int bm = b >> 6, kb = b & 63;
    int r = t >> 1, h = t & 1;
    const float4* xp = (const float4*)(x + (((size_t)(bm * 128 + r)) << 12) + kb * 64 + h * 32);
    float4 v0 = xp[0], v1 = xp[1], v2 = xp[2], v3 = xp[3];
    float4 v4 = xp[4], v5 = xp[5], v6 = xp[6], v7 = xp[7];
    union { ushort_t us[8]; int4 v; } e0, e1, o0, o1;
    e0.us[0] = f2bf(v0.x); o0.us[0] = f2bf(v0.y);
    e0.us[1] = f2bf(v0.z); o0.us[1] = f2bf(v0.w);
    e0.us[2] = f2bf(v1.x); o0.us[2] = f2bf(v1.y);
    e0.us[3] = f2bf(v1.z); o0.us[3] = f2bf(v1.w);
    e0.us[4] = f2bf(v2.x); o0.us[4] = f2bf(v2.y);
    e0.us[5] = f2bf(v2.z); o0.us[5] = f2bf(v2.w);
    e0.us[6] = f2bf(v3.x); o0.us[6] = f2bf(v3.y);
    e0.us[7] = f2bf(v3.z); o0.us[7] = f2bf(v3.w);
    e1.us[0] = f2bf(v4.x); o1.us[0] = f2bf(v4.y);
    e1.us[1] = f2bf(v4.z); o1.us[1] = f2bf(v4.w);
    e1.us[2] = f2bf(v5.x); o1.us[2] = f2bf(v5.y);
    e1.us[3] = f2bf(v5.z); o1.us[3] = f2bf(v5.w);
    e1.us[4] = f2bf(v6.x); o1.us[4] = f2bf(v6.y);
    e1.us[5] = f2bf(v6.z); o1.us[5] = f2bf(v6.w);
    e1.us[6] = f2bf(v7.x); o1.us[6] = f2bf(v7.y);
    e1.us[7] = f2bf(v7.z); o1.us[7] = f2bf(v7.w);
    size_t tb = ((size_t)(bm * 64 + kb)) << 12;      // tile base (elems)
    int c0 = (2 * h) * 1024 + r * 8;                 // g = 2h
    int c1 = c0 + 1024;                              // g = 2h+1
    *(int4*)(Ae + tb + c0) = e0.v;
    *(int4*)(Ae + tb + c1) = e1.v;
    *(int4*)(Ao + tb + c0) = o0.v;
    *(int4*)(Ao + tb + c1) = o1.v;
  } else {
    int b2 = b - 2048;
    int plane = b2 >> 10;            // 0 = Ce (even n), 1 = Co (odd n)
    int bn = (b2 & 1023) >> 6, kb = b2 & 63;
    ushort_t* T = plane ? Co : Ce;
    size_t tb = ((size_t)(bn * 64 + kb)) << 12;
    const float s = 3.14159265358979f / 8192.0f;     // pi/(2N)
#pragma unroll
    for (int half = 0; half < 2; ++half) {
      int cc = t + half * 256;       // chunk index within tile [0,512)
      int g = cc >> 7, r = cc & 127;
      int p = bn * 128 + r;
      int tp = 2 * p + 1;
      int ni = kb * 32 + g * 8;
      union { ushort_t us[8]; int4 v; } pk;
#pragma unroll
      for (int jj = 0; jj < 8; ++jj) {
        int n = 2 * (ni + jj) + plane;
        int ang = (n * tp) & 16383;  // mod 4N: exact int reduction
        float c = (n == 0) ? 1.0f : 2.0f * __cosf(s * (float)ang);
        pk.us[jj] = f2bf(c);
      }
      *(int4*)(T + tb + cc * 8) = pk.v;
    }
  }
}

// Fused dual GEMM + butterfly. Block 128m x 128p, BK=32, double-buffered,
// 4 waves 2x2, wave tile 64x64 per GEMM, frags 4x4, dual acc E/O.
// LDS: S[32768] elems = 2 bufs x {AsE,AsO,BsE,BsO} x 4096. Per iter:
//   STAGE next tile (8 GLDS, linear 1KB/wave-issue) -> ds_read 16 frags
//   (256B-contiguous phases, 0 conflicts) -> 32 MFMAs -> 1 barrier.
__global__ __launch_bounds__(256, 2) void gemm_fused(const ushort_t* __restrict__ Ae,
                                                     const ushort_t* __restrict__ Ao,
                                                     const ushort_t* __restrict__ Ce,
                                                     const ushort_t* __restrict__ Co,
                                                     float* __restrict__ out) {
  __shared__ __align__(16) ushort_t S[32768];   // 64 KB

  const int tid = threadIdx.x;
  const int wid = tid >> 6;
  const int lane = tid & 63;

  const int bm = blockIdx.y;   // m-tile index (128 rows)
  const int bn = blockIdx.x;   // p-tile index (128 cols)

  const int wm = (wid & 1) * 64;
  const int wn = (wid >> 1) * 64;
  const int lrow = lane & 15;

  floatx4 accE[4][4] = {};
  floatx4 accO[4][4] = {};

  const int lb = wid * 512;                  // wave elem base within an issue
  const ushort_t* pAe = Ae + (((size_t)bm * NKB) << 12) + (tid << 3);
  const ushort_t* pAo = Ao + (((size_t)bm * NKB) << 12) + (tid << 3);
  const ushort_t* pBe = Ce + (((size_t)bn * NKB) << 12) + (tid << 3);
  const ushort_t* pBo = Co + (((size_t)bn * NKB) << 12) + (tid << 3);

#define GLDS(src, dst) __builtin_amdgcn_global_load_lds( \
      (const __attribute__((address_space(1))) void*)(src), \
      (__attribute__((address_space(3))) void*)(dst), 16, 0, 0)

#define STAGE(bufoff, t) do { \
    size_t so_ = ((size_t)(t)) << 12; \
    _Pragma("unroll") \
    for (int i_ = 0; i_ < 2; ++i_) { \
      GLDS(pAe + so_ + i_ * 2048, S + (bufoff) + i_ * 2048 + lb); \
      GLDS(pAo + so_ + i_ * 2048, S + (bufoff) + 4096 + i_ * 2048 + lb); \
      GLDS(pBe + so_ + i_ * 2048, S + (bufoff) + 8192 + i_ * 2048 + lb); \
      GLDS(pBo + so_ + i_ * 2048, S + (bufoff) + 12288 + i_ * 2048 + lb); \
    } } while (0)

  const int g1024 = (lane >> 4) << 10;   // k-chunk * 1024 elems
  const int rb8 = lrow << 3;

#define COMPUTE(bufoff) do { \
    bf16x8 bE_[4], bO_[4]; \
    _Pragma("unroll") \
    for (int f_ = 0; f_ < 4; ++f_) { \
      int off_ = (bufoff) + g1024 + rb8 + ((wn + f_ * 16) << 3); \
      bE_[f_] = *(const bf16x8*)(S + 8192 + off_); \
      bO_[f_] = *(const bf16x8*)(S + 12288 + off_); \
    } \
    _Pragma("unroll") \
    for (int im_ = 0; im_ < 4; ++im_) { \
      int off_ = (bufoff) + g1024 + rb8 + ((wm + im_ * 16) << 3); \
      bf16x8 aE_ = *(const bf16x8*)(S + off_); \
      bf16x8 aO_ = *(const bf16x8*)(S + 4096 + off_); \
      _Pragma("unroll") \
      for (int jn_ = 0; jn_ < 4; ++jn_) { \
        accE[im_][jn_] = __builtin_amdgcn_mfma_f32_16x16x32_bf16(aE_, bE_[jn_], accE[im_][jn_], 0, 0, 0); \
        accO[im_][jn_] = __builtin_amdgcn_mfma_f32_16x16x32_bf16(aO_, bO_[jn_], accO[im_][jn_], 0, 0, 0); \
      } \
    } } while (0)

  STAGE(0, 0);
  __syncthreads();
  for (int t = 0; t < NKB - 1; ++t) {
    const int cur = (t & 1) << 14;        // 0 / 16384
    STAGE(cur ^ 16384, t + 1);            // prefetch next tile into other buf
    COMPUTE(cur);
    __syncthreads();                      // drains vmcnt+lgkm; one/iter
  }
  COMPUTE(16384);                         // t = 63 -> buf 1

#undef GLDS
#undef STAGE
#undef COMPUTE

  // Epilogue butterfly. C/D mapping: col=lane&15, row=(lane>>4)*4+r.
#pragma unroll
  for (int im = 0; im < 4; ++im) {
    int rb = bm * BM + wm + im * 16 + (lane >> 4) * 4;
#pragma unroll
    for (int jn = 0; jn < 4; ++jn) {
      int p = bn * BN + wn + jn * 16 + lrow;
      float* lo = out + (size_t)rb * Nfull + p;
      float* hi = out + (size_t)rb * Nfull + (Nfull - 1 - p);
#pragma unroll
      for (int r = 0; r < 4; ++r) {
        float e = accE[im][jn][r];
        float o = accO[im][jn][r];
        lo[(size_t)r * Nfull] = e + o;
        hi[(size_t)r * Nfull] = e - o;
      }
    }
  }
}

extern "C" void kernel_launch(void* const* d_in, const int* in_sizes, int n_in,
                              void* d_out, int out_size, void* d_ws, size_t ws_size,
                              hipStream_t stream) {
  const float* x = (const float*)d_in[0];
  float* out = (float*)d_out;
  ushort_t* Ae = (ushort_t*)d_ws;                      // 16 MB (tiled)
  ushort_t* Ao = Ae + (size_t)8 * 1024 * 1024;         // 16 MB
  ushort_t* Ce = Ao + (size_t)8 * 1024 * 1024;         // 8 MB
  ushort_t* Co = Ce + (size_t)4 * 1024 * 1024;         // 8 MB

  prep_kernel<<<4096, 256, 0, stream>>>(x, Ae, Ao, Ce, Co);

  dim3 grid(Ph / BN, Md / BM);  // 16 x 32 = 512 blocks = 2/CU
  gemm_fused<<<grid, 256, 0, stream>>>(Ae, Ao, Ce, Co, out);
}

// Round 4
// 176.473 us; speedup vs baseline: 1.3427x; 1.0119x over previous
//
#include <hip/hip_runtime.h>
#include <stdint.h>

// IDCT (DCT-III, DREAMPlace scaling) via even/odd split, fully fused:
//   E[m][p] = sum_{n even} x[m][n]*c(n,p),  O[m][p] = sum_{n odd} ...,
//   out[p] = E+O, out[N-1-p] = E-O   (c(n,N-1-p) = (-1)^n c(n,p)).
// R9 (from R8: gemm 74us, MfmaUtil 37%, conflicts 0 — 2-phase prefetch was
// a NULL because __syncthreads drains vmcnt(0), force-completing the
// just-issued prefetch every iteration):
//   Counted-vmcnt depth-2 pipeline (T3+T4+T5, m230/m201-verified pattern):
//   raw s_barrier + inline-asm s_waitcnt vmcnt(8) (NEVER 0 in main loop).
//   Prologue stages tiles 0,1; iter t: wait vmcnt(8) [tile t landed, t+1 in
//   flight] -> barrier -> setprio(1) MFMA setprio(0) -> barrier -> stage
//   tile t+2 into freed buffer. Each stage gets a full compute iter + slack
//   to land. Tail peeled (vmcnt(8), then vmcnt(0)).
//   Cycle model/CU/iter-pair: MFMA 1240, LDS 1500, L2-stage 1170; R8
//   measured 2780 (no overlap); target ~1600-1800 -> gemm 50-58us.
// Prep unchanged from R8 (one variable per round).
// ws: Ae_t 16MB | Ao_t 16MB | Ce_t 8MB | Co_t 8MB = 48MB.
// Tile layout: plane[(tile = bt*64 + kb)*4096 + g*1024 + r*8 + j]
//   = elem(row=r, k=kb*32+g*8+j) of the (bt,kb) 128x32 tile.

#define Md 4096
#define Nfull 4096
#define Ph 2048   // half output width
#define Kh 2048   // half reduction
#define BM 128
#define BN 128
#define BK 32
#define NKB 64    // Kh/BK k-blocks
#define TILE 4096 // elems per tile (128 rows x 32 k)

typedef short bf16x8 __attribute__((ext_vector_type(8)));
typedef float floatx4 __attribute__((ext_vector_type(4)));
typedef unsigned short ushort_t;

__device__ __forceinline__ ushort_t f2bf(float f) {
  union { float f; uint32_t u; } v; v.f = f;
  uint32_t u = v.u;
  return (ushort_t)((u + 0x7fffu + ((u >> 16) & 1u)) >> 16);
}

// blocks [0,2048): deinterleave x into tiled Ae/Ao. Block=(bm,kb) tile pair;
//   thread t: row r=t>>1, half h=t&1 -> reads 32 consecutive floats (128B),
//   writes 2 int4 per plane at tiled offsets (two 512B segments/instr).
// blocks [2048,4096): cosine tables straight into tiled layout, 2 chunks/thr.
__global__ __launch_bounds__(256) void prep_kernel(const float* __restrict__ x,
                                                   ushort_t* __restrict__ Ae,
                                                   ushort_t* __restrict__ Ao,
                                                   ushort_t* __restrict__ Ce,
                                                   ushort_t* __restrict__ Co) {
  int b = blockIdx.x;
  int t = threadIdx.x;
  if (b < 2048) {
    int bm = b >> 6, kb = b & 63;
    int r = t >> 1, h = t & 1;
    const float4* xp = (const float4*)(x + (((size_t)(bm * 128 + r)) << 12) + kb * 64 + h * 32);
    float4 v0 = xp[0], v1 = xp[1], v2 = xp[2], v3 = xp[3];
    float4 v4 = xp[4], v5 = xp[5], v6 = xp[6], v7 = xp[7];
    union { ushort_t us[8]; int4 v; } e0, e1, o0, o1;
    e0.us[0] = f2bf(v0.x); o0.us[0] = f2bf(v0.y);
    e0.us[1] = f2bf(v0.z); o0.us[1] = f2bf(v0.w);
    e0.us[2] = f2bf(v1.x); o0.us[2] = f2bf(v1.y);
    e0.us[3] = f2bf(v1.z); o0.us[3] = f2bf(v1.w);
    e0.us[4] = f2bf(v2.x); o0.us[4] = f2bf(v2.y);
    e0.us[5] = f2bf(v2.z); o0.us[5] = f2bf(v2.w);
    e0.us[6] = f2bf(v3.x); o0.us[6] = f2bf(v3.y);
    e0.us[7] = f2bf(v3.z); o0.us[7] = f2bf(v3.w);
    e1.us[0] = f2bf(v4.x); o1.us[0] = f2bf(v4.y);
    e1.us[1] = f2bf(v4.z); o1.us[1] = f2bf(v4.w);
    e1.us[2] = f2bf(v5.x); o1.us[2] = f2bf(v5.y);
    e1.us[3] = f2bf(v5.z); o1.us[3] = f2bf(v5.w);
    e1.us[4] = f2bf(v6.x); o1.us[4] = f2bf(v6.y);
    e1.us[5] = f2bf(v6.z); o1.us[5] = f2bf(v6.w);
    e1.us[6] = f2bf(v7.x); o1.us[6] = f2bf(v7.y);
    e1.us[7] = f2bf(v7.z); o1.us[7] = f2bf(v7.w);
    size_t tb = ((size_t)(bm * 64 + kb)) << 12;      // tile base (elems)
    int c0 = (2 * h) * 1024 + r * 8;                 // g = 2h
    int c1 = c0 + 1024;                              // g = 2h+1
    *(int4*)(Ae + tb + c0) = e0.v;
    *(int4*)(Ae + tb + c1) = e1.v;
    *(int4*)(Ao + tb + c0) = o0.v;
    *(int4*)(Ao + tb + c1) = o1.v;
  } else {
    int b2 = b - 2048;
    int plane = b2 >> 10;            // 0 = Ce (even n), 1 = Co (odd n)
    int bn = (b2 & 1023) >> 6, kb = b2 & 63;
    ushort_t* T = plane ? Co : Ce;
    size_t tb = ((size_t)(bn * 64 + kb)) << 12;
    const float s = 3.14159265358979f / 8192.0f;     // pi/(2N)
#pragma unroll
    for (int half = 0; half < 2; ++half) {
      int cc = t + half * 256;       // chunk index within tile [0,512)
      int g = cc >> 7, r = cc & 127;
      int p = bn * 128 + r;
      int tp = 2 * p + 1;
      int ni = kb * 32 + g * 8;
      union { ushort_t us[8]; int4 v; } pk;
#pragma unroll
      for (int jj = 0; jj < 8; ++jj) {
        int n = 2 * (ni + jj) + plane;
        int ang = (n * tp) & 16383;  // mod 4N: exact int reduction
        float c = (n == 0) ? 1.0f : 2.0f * __cosf(s * (float)ang);
        pk.us[jj] = f2bf(c);
      }
      *(int4*)(T + tb + cc * 8) = pk.v;
    }
  }
}

// Fused dual GEMM + butterfly. Block 128m x 128p, BK=32, double-buffered,
// 4 waves 2x2, wave tile 64x64 per GEMM, frags 4x4, dual acc E/O.
// LDS: S[32768] elems = 2 bufs x {AsE,AsO,BsE,BsO} x 4096.
// Counted-vmcnt depth-2 schedule: STAGE = 8 GLDS/wave; main-loop wait is
// vmcnt(8) (one stage in flight across the barrier), never 0.
__global__ __launch_bounds__(256, 2) void gemm_fused(const ushort_t* __restrict__ Ae,
                                                     const ushort_t* __restrict__ Ao,
                                                     const ushort_t* __restrict__ Ce,
                                                     const ushort_t* __restrict__ Co,
                                                     float* __restrict__ out) {
  __shared__ __align__(16) ushort_t S[32768];   // 64 KB

  const int tid = threadIdx.x;
  const int wid = tid >> 6;
  const int lane = tid & 63;

  const int bm = blockIdx.y;   // m-tile index (128 rows)
  const int bn = blockIdx.x;   // p-tile index (128 cols)

  const int wm = (wid & 1) * 64;
  const int wn = (wid >> 1) * 64;
  const int lrow = lane & 15;

  floatx4 accE[4][4] = {};
  floatx4 accO[4][4] = {};

  const int lb = wid * 512;                  // wave elem base within an issue
  const ushort_t* pAe = Ae + (((size_t)bm * NKB) << 12) + (tid << 3);
  const ushort_t* pAo = Ao + (((size_t)bm * NKB) << 12) + (tid << 3);
  const ushort_t* pBe = Ce + (((size_t)bn * NKB) << 12) + (tid << 3);
  const ushort_t* pBo = Co + (((size_t)bn * NKB) << 12) + (tid << 3);

#define GLDS(src, dst) __builtin_amdgcn_global_load_lds( \
      (const __attribute__((address_space(1))) void*)(src), \
      (__attribute__((address_space(3))) void*)(dst), 16, 0, 0)

#define STAGE(bufoff, t) do { \
    size_t so_ = ((size_t)(t)) << 12; \
    _Pragma("unroll") \
    for (int i_ = 0; i_ < 2; ++i_) { \
      GLDS(pAe + so_ + i_ * 2048, S + (bufoff) + i_ * 2048 + lb); \
      GLDS(pAo + so_ + i_ * 2048, S + (bufoff) + 4096 + i_ * 2048 + lb); \
      GLDS(pBe + so_ + i_ * 2048, S + (bufoff) + 8192 + i_ * 2048 + lb); \
      GLDS(pBo + so_ + i_ * 2048, S + (bufoff) + 12288 + i_ * 2048 + lb); \
    } } while (0)

  const int g1024 = (lane >> 4) << 10;   // k-chunk * 1024 elems
  const int rb8 = lrow << 3;

#define COMPUTE(bufoff) do { \
    bf16x8 bE_[4], bO_[4]; \
    _Pragma("unroll") \
    for (int f_ = 0; f_ < 4; ++f_) { \
      int off_ = (bufoff) + g1024 + rb8 + ((wn + f_ * 16) << 3); \
      bE_[f_] = *(const bf16x8*)(S + 8192 + off_); \
      bO_[f_] = *(const bf16x8*)(S + 12288 + off_); \
    } \
    __builtin_amdgcn_s_setprio(1); \
    _Pragma("unroll") \
    for (int im_ = 0; im_ < 4; ++im_) { \
      int off_ = (bufoff) + g1024 + rb8 + ((wm + im_ * 16) << 3); \
      bf16x8 aE_ = *(const bf16x8*)(S + off_); \
      bf16x8 aO_ = *(const bf16x8*)(S + 4096 + off_); \
      _Pragma("unroll") \
      for (int jn_ = 0; jn_ < 4; ++jn_) { \
        accE[im_][jn_] = __builtin_amdgcn_mfma_f32_16x16x32_bf16(aE_, bE_[jn_], accE[im_][jn_], 0, 0, 0); \
        accO[im_][jn_] = __builtin_amdgcn_mfma_f32_16x16x32_bf16(aO_, bO_[jn_], accO[im_][jn_], 0, 0, 0); \
      } \
    } \
    __builtin_amdgcn_s_setprio(0); \
  } while (0)

#define WAITVM(n) do { \
    asm volatile("s_waitcnt vmcnt(" #n ")" ::: "memory"); \
    __builtin_amdgcn_sched_barrier(0); \
  } while (0)

  // Prologue: stage tiles 0 and 1 (depth-2 pipeline).
  STAGE(0, 0);
  STAGE(16384, 1);

  for (int t = 0; t < NKB - 2; ++t) {
    const int cur = (t & 1) << 14;        // 0 / 16384
    WAITVM(8);                            // tile t landed; t+1 in flight
    __builtin_amdgcn_s_barrier();         // all waves' portions visible
    COMPUTE(cur);
    __builtin_amdgcn_s_barrier();         // all waves done reading buf cur
    STAGE(cur, t + 2);                    // refill freed buffer
  }
  // t = NKB-2 (62): buf 0.
  WAITVM(8);
  __builtin_amdgcn_s_barrier();
  COMPUTE(0);
  // t = NKB-1 (63): buf 1 — last stage must be fully landed.
  WAITVM(0);
  __builtin_amdgcn_s_barrier();
  COMPUTE(16384);

#undef GLDS
#undef STAGE
#undef COMPUTE
#undef WAITVM

  // Epilogue butterfly. C/D mapping: col=lane&15, row=(lane>>4)*4+r.
#pragma unroll
  for (int im = 0; im < 4; ++im) {
    int rb = bm * BM + wm + im * 16 + (lane >> 4) * 4;
#pragma unroll
    for (int jn = 0; jn < 4; ++jn) {
      int p = bn * BN + wn + jn * 16 + lrow;
      float* lo = out + (size_t)rb * Nfull + p;
      float* hi = out + (size_t)rb * Nfull + (Nfull - 1 - p);
#pragma unroll
      for (int r = 0; r < 4; ++r) {
        float e = accE[im][jn][r];
        float o = accO[im][jn][r];
        lo[(size_t)r * Nfull] = e + o;
        hi[(size_t)r * Nfull] = e - o;
      }
    }
  }
}

extern "C" void kernel_launch(void* const* d_in, const int* in_sizes, int n_in,
                              void* d_out, int out_size, void* d_ws, size_t ws_size,
                              hipStream_t stream) {
  const float* x = (const float*)d_in[0];
  float* out = (float*)d_out;
  ushort_t* Ae = (ushort_t*)d_ws;                      // 16 MB (tiled)
  ushort_t* Ao = Ae + (size_t)8 * 1024 * 1024;         // 16 MB
  ushort_t* Ce = Ao + (size_t)8 * 1024 * 1024;         // 8 MB
  ushort_t* Co = Ce + (size_t)4 * 1024 * 1024;         // 8 MB

  prep_kernel<<<4096, 256, 0, stream>>>(x, Ae, Ao, Ce, Co);

  dim3 grid(Ph / BN, Md / BM);  // 16 x 32 = 512 blocks = 2/CU
  gemm_fused<<<grid, 256, 0, stream>>>(Ae, Ao, Ce, Co, out);
}